// Round 13
// baseline (327.657 us; speedup 1.0000x reference)
//
#include <hip/hip_runtime.h>
#include <math.h>

#define SEQ   2048
#define DM    1024
#define NH    16
#define DH    64
#define DFF   4096
#define KVSPLIT 2

typedef __bf16 bf16;
using bf16x8 = __attribute__((ext_vector_type(8))) __bf16;
using bf16x4 = __attribute__((ext_vector_type(4))) __bf16;
using f32x4  = __attribute__((ext_vector_type(4))) float;

__device__ __forceinline__ unsigned short f2bfu(float f) {
    unsigned int u = __float_as_uint(f);
    u += 0x7FFF + ((u >> 16) & 1);          // round-to-nearest-even
    return (unsigned short)(u >> 16);
}
__device__ __forceinline__ bf16 f2bf(float f) {
    unsigned short s = f2bfu(f);
    return __builtin_bit_cast(bf16, s);
}

// single-instruction packed f32x2 -> bf16x2 (RTNE); no builtin on gfx950.
__device__ __forceinline__ unsigned cvt_pk_bf16(float lo, float hi) {
    unsigned r;
    asm("v_cvt_pk_bf16_f32 %0, %1, %2" : "=v"(r) : "v"(lo), "v"(hi));
    return r;
}

// async global->LDS, 16B per lane. lds base must be wave-uniform; HW adds lane*16.
__device__ __forceinline__ void gll16(const bf16* g, bf16* lds_base) {
    __builtin_amdgcn_global_load_lds(
        (const __attribute__((address_space(1))) unsigned int*)g,
        (__attribute__((address_space(3))) unsigned int*)lds_base, 16, 0, 0);
}

// XCD-aware block swizzle (T1): attention only (FETCH 36.9 -> 12.3 MB, r7).
__device__ __forceinline__ int xcd_swz(int wid, int nwg) {
    return (wid & 7) * (nwg >> 3) + (wid >> 3);
}

// ---------------------------------------------------------------------------
// fp32 -> bf16 conversions: single-tensor and 6-way segmented (blockIdx.y)
// ---------------------------------------------------------------------------
__global__ __launch_bounds__(256) void conv_k(const float* __restrict__ src,
                                              bf16* __restrict__ dst, int n) {
    int i = (blockIdx.x * 256 + threadIdx.x) * 4;
    if (i >= n) return;
    float4 v = *(const float4*)(src + i);
    ushort4 o;
    o.x = f2bfu(v.x); o.y = f2bfu(v.y); o.z = f2bfu(v.z); o.w = f2bfu(v.w);
    *(ushort4*)((unsigned short*)dst + i) = o;
}

struct ConvSeg  { const float* src; bf16* dst; int n; };
struct ConvSegs { ConvSeg s[6]; };

__global__ __launch_bounds__(256) void conv_multi_k(ConvSegs cs) {
    ConvSeg sg = cs.s[blockIdx.y];
    int i = (blockIdx.x * 256 + threadIdx.x) * 4;
    if (i >= sg.n) return;
    float4 v = *(const float4*)(sg.src + i);
    ushort4 o;
    o.x = f2bfu(v.x); o.y = f2bfu(v.y); o.z = f2bfu(v.z); o.w = f2bfu(v.w);
    *(ushort4*)((unsigned short*)sg.dst + i) = o;
}

// ---------------------------------------------------------------------------
// bf16 MFMA GEMM, BK=64, XOR-swizzled LDS (rule #21), ST-stage pipeline with
// counted vmcnt (T3/T4): ST-1 tiles' loads stay in flight; steady-state wait
// is vmcnt((ST-1)*LPS) -- never drained until the tail. 512 threads = 8
// waves. ST=3 for 128x64/64x128 tiles (72KB LDS, still 2 blocks/CU); ST=2
// for 128x128 (96KB at ST=3 would drop to 1 block/CU -- the r3 cliff).
// ---------------------------------------------------------------------------
struct GemmPtrs {
    const bf16* W[3];
    const float* bias[3];
    float* out32[3];
    bf16*  out16[3];
    float scale[3];
};

template<int BM, int BN, int BK, int WM, int ST>
__global__ __launch_bounds__(512) void gemm_bf16_k(
    const bf16* __restrict__ A, GemmPtrs p, int N, int K, int relu)
{
    constexpr int WN  = 8 / WM;
    constexpr int TM  = BM / WM / 16;
    constexpr int TN  = BN / WN / 16;
    constexpr int KK  = BK / 32;
    constexpr int CH  = BK / 8;
    constexpr int LPS = (BM + BN) * BK / 4096;   // gll16 per thread per stage
    __shared__ bf16 As[ST][BM][BK];
    __shared__ bf16 Ws[ST][BN][BK];

    const int t    = threadIdx.x;
    const int lane = t & 63;
    const int wave = t >> 6;
    const int quad = lane >> 4;
    const int l15  = lane & 15;
    const int wm   = (wave / WN) * (BM / WM);
    const int wn   = (wave % WN) * (BN / WN);
    const int m0   = blockIdx.y * BM;
    const int n0   = blockIdx.x * BN;
    const int xm   = l15 & (CH - 1);
    const bf16* __restrict__ W = p.W[blockIdx.z];

    f32x4 acc[TM][TN];
    #pragma unroll
    for (int i = 0; i < TM; ++i)
        #pragma unroll
        for (int j = 0; j < TN; ++j)
            acc[i][j] = f32x4{0.f, 0.f, 0.f, 0.f};

    auto stage = [&](int buf, int k0) {
        #pragma unroll
        for (int s = 0; s < BM * BK / 4096; ++s) {
            int base = s * 512 + wave * 64;
            int idx  = base + lane;
            int row  = idx / CH;
            int c    = idx % CH;
            gll16(A + (long)(m0 + row) * K + k0 + ((c ^ (row & (CH - 1))) * 8),
                  &As[buf][0][0] + (long)base * 8);
        }
        #pragma unroll
        for (int s = 0; s < BN * BK / 4096; ++s) {
            int base = s * 512 + wave * 64;
            int idx  = base + lane;
            int row  = idx / CH;
            int c    = idx % CH;
            gll16(W + (long)(n0 + row) * K + k0 + ((c ^ (row & (CH - 1))) * 8),
                  &Ws[buf][0][0] + (long)base * 8);
        }
    };

    stage(0, 0);
    if (ST == 3 && BK < K) stage(1, BK);
    int cur = 0;
    for (int k0 = 0; k0 < K; k0 += BK) {
        if (k0 + (ST - 1) * BK < K) {
            int nxt = cur + ST - 1; if (nxt >= ST) nxt -= ST;
            stage(nxt, k0 + (ST - 1) * BK);
            asm volatile("s_waitcnt vmcnt(%0)" :: "i"((ST - 1) * LPS) : "memory");
        } else if (ST == 3 && k0 + BK < K) {
            asm volatile("s_waitcnt vmcnt(%0)" :: "i"(LPS) : "memory");
        } else {
            asm volatile("s_waitcnt vmcnt(0)" ::: "memory");
        }
        __builtin_amdgcn_s_barrier();
        __builtin_amdgcn_sched_barrier(0);

        bf16x8 a[TM][KK], b[TN][KK];
        #pragma unroll
        for (int i = 0; i < TM; ++i)
            #pragma unroll
            for (int kk = 0; kk < KK; ++kk)
                a[i][kk] = *(const bf16x8*)
                    &As[cur][wm + i * 16 + l15][((kk * 4 + quad) ^ xm) * 8];
        #pragma unroll
        for (int j = 0; j < TN; ++j)
            #pragma unroll
            for (int kk = 0; kk < KK; ++kk)
                b[j][kk] = *(const bf16x8*)
                    &Ws[cur][wn + j * 16 + l15][((kk * 4 + quad) ^ xm) * 8];
        #pragma unroll
        for (int kk = 0; kk < KK; ++kk)
            #pragma unroll
            for (int i = 0; i < TM; ++i)
                #pragma unroll
                for (int j = 0; j < TN; ++j)
                    acc[i][j] = __builtin_amdgcn_mfma_f32_16x16x32_bf16(
                        a[i][kk], b[j][kk], acc[i][j], 0, 0, 0);

        __builtin_amdgcn_sched_barrier(0);
        __builtin_amdgcn_s_barrier();
        if (++cur >= ST) cur = 0;
    }

    float* o32 = p.out32[blockIdx.z];
    bf16*  o16 = p.out16[blockIdx.z];
    const float* bias = p.bias[blockIdx.z];
    const float scl = p.scale[blockIdx.z];
    #pragma unroll
    for (int j = 0; j < TN; ++j) {
        int n = n0 + wn + j * 16 + l15;
        float bv = bias[n];
        #pragma unroll
        for (int i = 0; i < TM; ++i) {
            #pragma unroll
            for (int r = 0; r < 4; ++r) {
                int m = m0 + wm + i * 16 + quad * 4 + r;
                float v = (acc[i][j][r] + bv) * scl;
                if (relu) v = fmaxf(v, 0.f);
                if (o32) o32[(long)m * N + n] = v;
                if (o16) o16[(long)m * N + n] = f2bf(v);
            }
        }
    }
}

// ---------------------------------------------------------------------------
// Split-K GEMM, BK=64, same swizzle + ST-stage pipeline + 512 threads.
// ---------------------------------------------------------------------------
template<int BM, int BN, int BK, int KS, int WM, int ST>
__global__ __launch_bounds__(512) void gemm_splitk_k(
    const bf16* __restrict__ A, const bf16* __restrict__ W,
    float* __restrict__ part, int N, int K)
{
    constexpr int WN  = 8 / WM;
    constexpr int TM  = BM / WM / 16;
    constexpr int TN  = BN / WN / 16;
    constexpr int KK  = BK / 32;
    constexpr int CH  = BK / 8;
    constexpr int LPS = (BM + BN) * BK / 4096;
    __shared__ bf16 As[ST][BM][BK];
    __shared__ bf16 Ws[ST][BN][BK];

    const int t    = threadIdx.x;
    const int lane = t & 63;
    const int wave = t >> 6;
    const int quad = lane >> 4;
    const int l15  = lane & 15;
    const int wm   = (wave / WN) * (BM / WM);
    const int wn   = (wave % WN) * (BN / WN);
    const int m0   = blockIdx.y * BM;
    const int n0   = blockIdx.x * BN;
    const int xm   = l15 & (CH - 1);
    const int Kp   = K / KS;
    const int klo  = blockIdx.z * Kp;
    const long MN  = (long)gridDim.y * BM * N;

    f32x4 acc[TM][TN];
    #pragma unroll
    for (int i = 0; i < TM; ++i)
        #pragma unroll
        for (int j = 0; j < TN; ++j)
            acc[i][j] = f32x4{0.f, 0.f, 0.f, 0.f};

    auto stage = [&](int buf, int k0) {
        #pragma unroll
        for (int s = 0; s < BM * BK / 4096; ++s) {
            int base = s * 512 + wave * 64;
            int idx  = base + lane;
            int row  = idx / CH;
            int c    = idx % CH;
            gll16(A + (long)(m0 + row) * K + k0 + ((c ^ (row & (CH - 1))) * 8),
                  &As[buf][0][0] + (long)base * 8);
        }
        #pragma unroll
        for (int s = 0; s < BN * BK / 4096; ++s) {
            int base = s * 512 + wave * 64;
            int idx  = base + lane;
            int row  = idx / CH;
            int c    = idx % CH;
            gll16(W + (long)(n0 + row) * K + k0 + ((c ^ (row & (CH - 1))) * 8),
                  &Ws[buf][0][0] + (long)base * 8);
        }
    };

    stage(0, klo);
    if (ST == 3 && klo + BK < klo + Kp) stage(1, klo + BK);
    int cur = 0;
    for (int k0 = klo; k0 < klo + Kp; k0 += BK) {
        if (k0 + (ST - 1) * BK < klo + Kp) {
            int nxt = cur + ST - 1; if (nxt >= ST) nxt -= ST;
            stage(nxt, k0 + (ST - 1) * BK);
            asm volatile("s_waitcnt vmcnt(%0)" :: "i"((ST - 1) * LPS) : "memory");
        } else if (ST == 3 && k0 + BK < klo + Kp) {
            asm volatile("s_waitcnt vmcnt(%0)" :: "i"(LPS) : "memory");
        } else {
            asm volatile("s_waitcnt vmcnt(0)" ::: "memory");
        }
        __builtin_amdgcn_s_barrier();
        __builtin_amdgcn_sched_barrier(0);

        bf16x8 a[TM][KK], b[TN][KK];
        #pragma unroll
        for (int i = 0; i < TM; ++i)
            #pragma unroll
            for (int kk = 0; kk < KK; ++kk)
                a[i][kk] = *(const bf16x8*)
                    &As[cur][wm + i * 16 + l15][((kk * 4 + quad) ^ xm) * 8];
        #pragma unroll
        for (int j = 0; j < TN; ++j)
            #pragma unroll
            for (int kk = 0; kk < KK; ++kk)
                b[j][kk] = *(const bf16x8*)
                    &Ws[cur][wn + j * 16 + l15][((kk * 4 + quad) ^ xm) * 8];
        #pragma unroll
        for (int kk = 0; kk < KK; ++kk)
            #pragma unroll
            for (int i = 0; i < TM; ++i)
                #pragma unroll
                for (int j = 0; j < TN; ++j)
                    acc[i][j] = __builtin_amdgcn_mfma_f32_16x16x32_bf16(
                        a[i][kk], b[j][kk], acc[i][j], 0, 0, 0);

        __builtin_amdgcn_sched_barrier(0);
        __builtin_amdgcn_s_barrier();
        if (++cur >= ST) cur = 0;
    }

    float* o = part + (long)blockIdx.z * MN;
    #pragma unroll
    for (int j = 0; j < TN; ++j) {
        int n = n0 + wn + j * 16 + l15;
        #pragma unroll
        for (int i = 0; i < TM; ++i)
            #pragma unroll
            for (int r = 0; r < 4; ++r) {
                int m = m0 + wm + i * 16 + quad * 4 + r;
                o[(long)m * N + n] = acc[i][j][r];
            }
    }
}

// ---------------------------------------------------------------------------
// Flash attention, QBLK=128 x 8 waves (512 threads), KVSPLIT=2, XCD-swizzled.
// Swapped QK^T (P lane-local), pre-scaled Q, cvt_pk P-pack, gll16 K staging
// with pre-swizzled source cols (rule #21), pair-packed V transpose
// (v_perm_b32) into virtual-key order:
//   key i=[kt1 kt0 q1 q0 r1 r0] -> v(i)=[kt1 q1 q0 r1 r0 kt0].
// ---------------------------------------------------------------------------
__global__ __launch_bounds__(512) void attn_mfma_k(
    const bf16* __restrict__ Q, const bf16* __restrict__ Kg,
    const bf16* __restrict__ Vg, bf16* __restrict__ Opart,
    float* __restrict__ lpart)
{
    __shared__ bf16 Kb[64][64];   // linear, gll16-staged, col-XOR by row&7
    __shared__ bf16 Vt[64][72];   // transposed V, virtual-key order + XOR swz

    const int nwg = gridDim.x * gridDim.y * gridDim.z;
    const int wid = blockIdx.x + gridDim.x * (blockIdx.y + gridDim.y * blockIdx.z);
    const int sw  = xcd_swz(wid, nwg);
    const int bx  = sw % gridDim.x;
    const int rem = sw / gridDim.x;
    const int h   = rem % gridDim.y;
    const int spl = rem / gridDim.y;
    const int q0  = bx * 128;

    const int t    = threadIdx.x;
    const int lane = t & 63;
    const int wave = t >> 6;       // 0..7: 8 waves x 16 queries = 128
    const int quad = lane >> 4;
    const int l15  = lane & 15;
    const int cb   = h * DH;
    const long SD  = (long)SEQ * DM;

    const int qrow = q0 + wave * 16 + l15;
    bf16x8 bQ[2];
    #pragma unroll
    for (int kh = 0; kh < 2; ++kh)
        bQ[kh] = *(const bf16x8*)(Q + (long)qrow * DM + cb + kh * 32 + quad * 8);

    f32x4 o_acc[4];
    #pragma unroll
    for (int dt = 0; dt < 4; ++dt) o_acc[dt] = f32x4{0.f, 0.f, 0.f, 0.f};
    float lsum = 0.f;

    const int kv_lo = spl * (SEQ / KVSPLIT);
    const int kv_hi = kv_lo + SEQ / KVSPLIT;

    for (int kv0 = kv_lo; kv0 < kv_hi; kv0 += 64) {
        __syncthreads();
        // --- K: one gll16 round (512 lanes x 16B = 8KB tile) ---
        {
            int row = t >> 3;
            int dg  = t & 7;
            gll16(Kg + (long)(kv0 + row) * DM + cb + ((dg ^ (row & 7)) * 8),
                  &Kb[0][0] + (wave * 64) * 8);
        }
        // --- V: one round, 4 b32 pair-packed writes/thread ---
        {
            int i  = t;                    // 0..511
            int h4 = (i & 1) * 4;
            int dg = (i >> 1) & 7;
            int kp = i >> 4;               // 0..31 pair index
            int k0 = ((kp & 16) << 1) | (kp & 15);   // keys with bit4 == 0
            const bf16* vb = Vg + (long)(kv0 + k0) * DM + cb + dg * 8 + h4;
            uint2 a0 = *(const uint2*)vb;
            uint2 a1 = *(const uint2*)(vb + 16 * DM);
            int vk0 = (k0 & 32) | ((k0 & 15) << 1);
            int col = vk0 ^ (dg * 8);
            int d0  = dg * 8 + h4;
            *(unsigned*)&Vt[d0 + 0][col] = __builtin_amdgcn_perm(a1.x, a0.x, 0x05040100u);
            *(unsigned*)&Vt[d0 + 1][col] = __builtin_amdgcn_perm(a1.x, a0.x, 0x07060302u);
            *(unsigned*)&Vt[d0 + 2][col] = __builtin_amdgcn_perm(a1.y, a0.y, 0x05040100u);
            *(unsigned*)&Vt[d0 + 3][col] = __builtin_amdgcn_perm(a1.y, a0.y, 0x07060302u);
        }
        __syncthreads();

        // QK^T swapped: A = K rows (from LDS), B = Q.
        float p[16];
        #pragma unroll
        for (int kt = 0; kt < 4; ++kt) {
            int krow = kt * 16 + l15;
            bf16x8 a0 = *(const bf16x8*)&Kb[krow][(quad ^ (l15 & 7)) * 8];
            bf16x8 a1 = *(const bf16x8*)&Kb[krow][((4 + quad) ^ (l15 & 7)) * 8];
            f32x4 sv = f32x4{0.f, 0.f, 0.f, 0.f};
            sv = __builtin_amdgcn_mfma_f32_16x16x32_bf16(a0, bQ[0], sv, 0, 0, 0);
            sv = __builtin_amdgcn_mfma_f32_16x16x32_bf16(a1, bQ[1], sv, 0, 0, 0);
            #pragma unroll
            for (int r = 0; r < 4; ++r) p[kt * 4 + r] = exp2f(sv[r]);
        }

        #pragma unroll
        for (int i = 0; i < 16; ++i) lsum += p[i];

        // pack P into PV A-fragments: aP[c][j] = p[(2c+(j&1))*4 + (j>>1)]
        bf16x8 aP[2];
        #pragma unroll
        for (int c = 0; c < 2; ++c) {
            union { unsigned u[4]; bf16x8 v; } pk;
            #pragma unroll
            for (int w4 = 0; w4 < 4; ++w4)
                pk.u[w4] = cvt_pk_bf16(p[c * 8 + w4], p[c * 8 + 4 + w4]);
            aP[c] = pk.v;
        }

        #pragma unroll
        for (int dt = 0; dt < 4; ++dt) {
            int d   = dt * 16 + l15;
            int dgr = d >> 3;
            bf16x8 v0 = *(const bf16x8*)&Vt[d][(quad ^ dgr) * 8];
            bf16x8 v1 = *(const bf16x8*)&Vt[d][((4 + quad) ^ dgr) * 8];
            o_acc[dt] = __builtin_amdgcn_mfma_f32_16x16x32_bf16(aP[0], v0, o_acc[dt], 0, 0, 0);
            o_acc[dt] = __builtin_amdgcn_mfma_f32_16x16x32_bf16(aP[1], v1, o_acc[dt], 0, 0, 0);
        }
    }

    #pragma unroll
    for (int r = 0; r < 4; ++r) {
        int row = q0 + wave * 16 + quad * 4 + r;
        #pragma unroll
        for (int dt = 0; dt < 4; ++dt)
            Opart[(long)spl * SD + (long)row * DM + cb + dt * 16 + l15] =
                f2bf(o_acc[dt][r]);
    }
    lsum += __shfl_xor(lsum, 16);
    lsum += __shfl_xor(lsum, 32);
    if (quad == 0)
        lpart[((long)spl * NH + h) * SEQ + qrow] = lsum;
}

__global__ __launch_bounds__(256) void attn_reduce_k(
    const bf16* __restrict__ Opart, const float* __restrict__ lpart,
    bf16* __restrict__ O)
{
    const long SD = (long)SEQ * DM;
    long i = ((long)blockIdx.x * 256 + threadIdx.x) * 8;
    int row = (int)(i / DM);
    int h   = (int)((i % DM) / DH);

    float l = 0.f;
    #pragma unroll
    for (int k = 0; k < KVSPLIT; ++k)
        l += lpart[((long)k * NH + h) * SEQ + row];
    float inv = 1.f / l;

    float acc[8] = {};
    #pragma unroll
    for (int k = 0; k < KVSPLIT; ++k) {
        bf16x8 v = *(const bf16x8*)(Opart + (long)k * SD + i);
        #pragma unroll
        for (int j = 0; j < 8; ++j) acc[j] += (float)v[j];
    }
    bf16x8 o;
    #pragma unroll
    for (int j = 0; j < 8; ++j) o[j] = f2bf(acc[j] * inv);
    *(bf16x8*)(O + i) = o;
}

// ---------------------------------------------------------------------------
// Fused split-K reduce + bias + residual + LayerNorm. One block per row.
// ---------------------------------------------------------------------------
template<int NS>
__global__ __launch_bounds__(256) void ln_red_k(
    const float* __restrict__ part, const float* __restrict__ bias,
    const float* __restrict__ res, const float* __restrict__ g,
    const float* __restrict__ b, float* __restrict__ out32,
    bf16* __restrict__ out16)
{
    const long SD = (long)SEQ * DM;
    const int row = blockIdx.x;
    const int t   = threadIdx.x;
    const long off = (long)row * DM + (t << 2);

    float4 v = *(const float4*)(res + off);
    float4 bv0 = *(const float4*)(bias + (t << 2));
    v.x += bv0.x; v.y += bv0.y; v.z += bv0.z; v.w += bv0.w;
    #pragma unroll
    for (int z = 0; z < NS; ++z) {
        float4 pz = *(const float4*)(part + z * SD + off);
        v.x += pz.x; v.y += pz.y; v.z += pz.z; v.w += pz.w;
    }

    float s1 = v.x + v.y + v.z + v.w;
    float s2 = v.x * v.x + v.y * v.y + v.z * v.z + v.w * v.w;
    #pragma unroll
    for (int off2 = 32; off2 > 0; off2 >>= 1) {
        s1 += __shfl_xor(s1, off2);
        s2 += __shfl_xor(s2, off2);
    }
    __shared__ float red[8];
    int wid = t >> 6, lid = t & 63;
    if (lid == 0) { red[wid] = s1; red[4 + wid] = s2; }
    __syncthreads();
    s1 = red[0] + red[1] + red[2] + red[3];
    s2 = red[4] + red[5] + red[6] + red[7];

    float mu   = s1 * (1.f / DM);
    float var  = s2 * (1.f / DM) - mu * mu;
    float rstd = rsqrtf(var + 1e-5f);

    float4 gv = *(const float4*)(g + (t << 2));
    float4 bv = *(const float4*)(b + (t << 2));
    float4 ov;
    ov.x = (v.x - mu) * rstd * gv.x + bv.x;
    ov.y = (v.y - mu) * rstd * gv.y + bv.y;
    ov.z = (v.z - mu) * rstd * gv.z + bv.z;
    ov.w = (v.w - mu) * rstd * gv.w + bv.w;
    if (out32) *(float4*)(out32 + off) = ov;
    if (out16) {
        ushort4 o;
        o.x = f2bfu(ov.x); o.y = f2bfu(ov.y); o.z = f2bfu(ov.z); o.w = f2bfu(ov.w);
        *(ushort4*)((unsigned short*)out16 + off) = o;
    }
}

// ---------------------------------------------------------------------------
extern "C" void kernel_launch(void* const* d_in, const int* in_sizes, int n_in,
                              void* d_out, int out_size, void* d_ws, size_t ws_size,
                              hipStream_t stream)
{
    const float* x       = (const float*)d_in[0];
    const float* q_in_w  = (const float*)d_in[1];
    const float* q_in_b  = (const float*)d_in[2];
    const float* k_in_w  = (const float*)d_in[3];
    const float* k_in_b  = (const float*)d_in[4];
    const float* v_in_w  = (const float*)d_in[5];
    const float* v_in_b  = (const float*)d_in[6];
    const float* out_w   = (const float*)d_in[7];
    const float* out_b   = (const float*)d_in[8];
    const float* ffn1_w  = (const float*)d_in[9];
    const float* ffn1_b  = (const float*)d_in[10];
    const float* ffn2_w  = (const float*)d_in[11];
    const float* ffn2_b  = (const float*)d_in[12];
    const float* n1_g    = (const float*)d_in[13];
    const float* n1_b    = (const float*)d_in[14];
    const float* n2_g    = (const float*)d_in[15];
    const float* n2_b    = (const float*)d_in[16];
    const float* q_out_w = (const float*)d_in[17];
    const float* q_out_b = (const float*)d_in[18];
    const float* k_out_w = (const float*)d_in[19];
    const float* k_out_b = (const float*)d_in[20];
    const float* v_out_w = (const float*)d_in[21];
    const float* v_out_b = (const float*)d_in[22];

    float* out = (float*)d_out;
    const long SD = (long)SEQ * DM;
    const long MB = 1024 * 1024;

    // --- workspace layout, 48 MiB, lifetime-checked (Opart 8MB) ---
    char* w = (char*)d_ws;
    bf16*  xbf   = (bf16*)(w);
    float* lpart = (float*)(w);
    bf16*  qb    = (bf16*)(w + 4  * MB);
    bf16*  kb    = (bf16*)(w + 8  * MB);
    bf16*  vb    = (bf16*)(w + 12 * MB);
    bf16*  atnb  = (bf16*)(w + 16 * MB);
    float* h32   = (float*)(w);
    bf16*  h16   = (bf16*)(w + 8  * MB);
    float* P2    = (float*)(w + 8  * MB);
    bf16*  Opart = (bf16*)(w + 20 * MB);
    float* P1    = (float*)(w + 20 * MB);
    bf16*  f1    = (bf16*)(w + 24 * MB);
    bf16*  wqi   = (bf16*)(w + 32 * MB);
    bf16*  wki   = (bf16*)(w + 34 * MB);
    bf16*  wvi   = (bf16*)(w + 36 * MB);
    bf16*  wo    = (bf16*)(w + 38 * MB);
    bf16*  wf1   = (bf16*)(w + 40 * MB);
    bf16*  wf2   = (bf16*)(w + 40 * MB);
    bf16*  wqo   = (bf16*)(w + 24 * MB);
    bf16*  wko   = (bf16*)(w + 26 * MB);
    bf16*  wvo   = (bf16*)(w + 28 * MB);
    bf16*  ybf   = (bf16*)(w + 30 * MB);
    float* y32   = out + 3 * SD;

    dim3 blk(256);
    dim3 blk512(512);
    const int DD = DM * DM;
    const float SCL = 0.18033688f;   // 0.125 * log2(e), folded into Q

    // --- conv group 1: x + in/out-proj weights + ffn1 ---
    {
        ConvSegs cs;
        cs.s[0] = {x,      xbf, (int)SD};
        cs.s[1] = {q_in_w, wqi, DD};
        cs.s[2] = {k_in_w, wki, DD};
        cs.s[3] = {v_in_w, wvi, DD};
        cs.s[4] = {out_w,  wo,  DD};
        cs.s[5] = {ffn1_w, wf1, DM * DFF};
        conv_multi_k<<<dim3(DM * DFF / 1024, 6), blk, 0, stream>>>(cs);
    }

    // --- q/k/v in-projections (128x64 BK=64, ST=3, 768 blocks x 8 waves) ---
    {
        GemmPtrs p{};
        p.W[0] = wqi; p.W[1] = wki; p.W[2] = wvi;
        p.bias[0] = q_in_b; p.bias[1] = k_in_b; p.bias[2] = v_in_b;
        p.out16[0] = qb; p.out16[1] = kb; p.out16[2] = vb;
        p.scale[0] = SCL; p.scale[1] = 1.0f; p.scale[2] = 1.0f;
        gemm_bf16_k<128, 64, 64, 4, 3><<<dim3(DM / 64, SEQ / 128, 3), blk512, 0, stream>>>(
            xbf, p, DM, DM, 0);
    }

    // --- attention: QBLK=128 x 8 waves, kv-split x2 (512 blocks) + reduce ---
    attn_mfma_k<<<dim3(SEQ / 128, NH, KVSPLIT), blk512, 0, stream>>>(
        qb, kb, vb, Opart, lpart);
    attn_reduce_k<<<dim3((int)(SD / 2048)), blk, 0, stream>>>(Opart, lpart, atnb);

    // --- out-projection, split-K=2 (64x128 BK=64, ST=3, 512 blocks) -> P1 ---
    gemm_splitk_k<64, 128, 64, 2, 2, 3><<<dim3(DM / 128, SEQ / 64, 2), blk512, 0, stream>>>(
        atnb, wo, P1, DM, DM);

    // --- LN1 fused reduce: h = LN(x + P1 + out_b) ---
    ln_red_k<2><<<SEQ, blk, 0, stream>>>(P1, out_b, x, n1_g, n1_b, h32, h16);

    // --- FFN1 (128x128 BK=64, ST=2, 512 blocks x 8 waves, relu) ---
    {
        GemmPtrs p{};
        p.W[0] = wf1; p.bias[0] = ffn1_b; p.out16[0] = f1;
        p.scale[0] = 1.0f; p.scale[1] = 1.0f; p.scale[2] = 1.0f;
        gemm_bf16_k<128, 128, 64, 2, 2><<<dim3(DFF / 128, SEQ / 128, 1), blk512, 0, stream>>>(
            h16, p, DFF, DM, 1);
    }

    // --- conv wf2 (into dead wf1 region) ---
    conv_k<<<dim3(DM * DFF / 1024), blk, 0, stream>>>(ffn2_w, wf2, DM * DFF);

    // --- FFN2, split-K=2 (64x128 BK=64, ST=3, 512 blocks) -> P2 ---
    gemm_splitk_k<64, 128, 64, 2, 2, 3><<<dim3(DM / 128, SEQ / 64, 2), blk512, 0, stream>>>(
        f1, wf2, P2, DM, DFF);

    // --- conv group 3 (into dead f1 region) ---
    {
        ConvSegs cs;
        cs.s[0] = {q_out_w, wqo, DD};
        cs.s[1] = {k_out_w, wko, DD};
        cs.s[2] = {v_out_w, wvo, DD};
        cs.s[3] = cs.s[0]; cs.s[4] = cs.s[0]; cs.s[5] = cs.s[0];
        conv_multi_k<<<dim3(DD / 1024, 3), blk, 0, stream>>>(cs);
    }

    // --- LN2 fused reduce: y = LN(h + P2 + ffn2_b) ---
    ln_red_k<2><<<SEQ, blk, 0, stream>>>(P2, ffn2_b, h32, n2_g, n2_b, y32, ybf);

    // --- next-layer projections (128x64 BK=64, ST=3, 768 blocks x 8 waves) ---
    {
        GemmPtrs p{};
        p.W[0] = wqo; p.W[1] = wko; p.W[2] = wvo;
        p.bias[0] = q_out_b; p.bias[1] = k_out_b; p.bias[2] = v_out_b;
        p.out32[0] = out; p.out32[1] = out + SD; p.out32[2] = out + 2 * SD;
        p.scale[0] = 1.0f; p.scale[1] = 1.0f; p.scale[2] = 1.0f;
        gemm_bf16_k<128, 64, 64, 4, 3><<<dim3(DM / 64, SEQ / 128, 3), blk512, 0, stream>>>(
            ybf, p, DM, DM, 0);
    }
}

// Round 14
// 306.263 us; speedup vs baseline: 1.0699x; 1.0699x over previous
//
#include <hip/hip_runtime.h>
#include <math.h>

#define SEQ   2048
#define DM    1024
#define NH    16
#define DH    64
#define DFF   4096
#define KVSPLIT 2

typedef __bf16 bf16;
using bf16x8 = __attribute__((ext_vector_type(8))) __bf16;
using bf16x4 = __attribute__((ext_vector_type(4))) __bf16;
using f32x4  = __attribute__((ext_vector_type(4))) float;

__device__ __forceinline__ unsigned short f2bfu(float f) {
    unsigned int u = __float_as_uint(f);
    u += 0x7FFF + ((u >> 16) & 1);          // round-to-nearest-even
    return (unsigned short)(u >> 16);
}
__device__ __forceinline__ bf16 f2bf(float f) {
    unsigned short s = f2bfu(f);
    return __builtin_bit_cast(bf16, s);
}

// single-instruction packed f32x2 -> bf16x2 (RTNE); no builtin on gfx950.
__device__ __forceinline__ unsigned cvt_pk_bf16(float lo, float hi) {
    unsigned r;
    asm("v_cvt_pk_bf16_f32 %0, %1, %2" : "=v"(r) : "v"(lo), "v"(hi));
    return r;
}

// async global->LDS, 16B per lane. lds base must be wave-uniform; HW adds lane*16.
__device__ __forceinline__ void gll16(const bf16* g, bf16* lds_base) {
    __builtin_amdgcn_global_load_lds(
        (const __attribute__((address_space(1))) unsigned int*)g,
        (__attribute__((address_space(3))) unsigned int*)lds_base, 16, 0, 0);
}

// XCD-aware block swizzle (T1): attention only (FETCH 36.9 -> 12.3 MB, r7).
__device__ __forceinline__ int xcd_swz(int wid, int nwg) {
    return (wid & 7) * (nwg >> 3) + (wid >> 3);
}

// ---------------------------------------------------------------------------
// fp32 -> bf16 conversions: single-tensor and 6-way segmented (blockIdx.y)
// ---------------------------------------------------------------------------
__global__ __launch_bounds__(256) void conv_k(const float* __restrict__ src,
                                              bf16* __restrict__ dst, int n) {
    int i = (blockIdx.x * 256 + threadIdx.x) * 4;
    if (i >= n) return;
    float4 v = *(const float4*)(src + i);
    ushort4 o;
    o.x = f2bfu(v.x); o.y = f2bfu(v.y); o.z = f2bfu(v.z); o.w = f2bfu(v.w);
    *(ushort4*)((unsigned short*)dst + i) = o;
}

struct ConvSeg  { const float* src; bf16* dst; int n; };
struct ConvSegs { ConvSeg s[6]; };

__global__ __launch_bounds__(256) void conv_multi_k(ConvSegs cs) {
    ConvSeg sg = cs.s[blockIdx.y];
    int i = (blockIdx.x * 256 + threadIdx.x) * 4;
    if (i >= sg.n) return;
    float4 v = *(const float4*)(sg.src + i);
    ushort4 o;
    o.x = f2bfu(v.x); o.y = f2bfu(v.y); o.z = f2bfu(v.z); o.w = f2bfu(v.w);
    *(ushort4*)((unsigned short*)sg.dst + i) = o;
}

// ---------------------------------------------------------------------------
// bf16 MFMA GEMM, BK=64, XOR-swizzled LDS (rule #21), 2-phase dbuf with
// counted vmcnt (T3/T4), 512 threads = 8 waves. ST=3 regressed (r13: +21us,
// rotating buffer index defeats LDS-offset folding) -- depth 2 is the sweet
// spot. T5 setprio(1) wraps the MFMA cluster: 2 co-resident blocks/CU are at
// unsynchronized phases, so priority biases issue toward the MFMA-phase
// block while the other stages (cross-block role-split).
// ---------------------------------------------------------------------------
struct GemmPtrs {
    const bf16* W[3];
    const float* bias[3];
    float* out32[3];
    bf16*  out16[3];
    float scale[3];
};

template<int BM, int BN, int BK, int WM>
__global__ __launch_bounds__(512) void gemm_bf16_k(
    const bf16* __restrict__ A, GemmPtrs p, int N, int K, int relu)
{
    constexpr int WN  = 8 / WM;
    constexpr int TM  = BM / WM / 16;
    constexpr int TN  = BN / WN / 16;
    constexpr int KK  = BK / 32;
    constexpr int CH  = BK / 8;
    constexpr int LPS = (BM + BN) * BK / 4096;   // gll16 per thread per stage
    __shared__ bf16 As[2][BM][BK];
    __shared__ bf16 Ws[2][BN][BK];

    const int t    = threadIdx.x;
    const int lane = t & 63;
    const int wave = t >> 6;
    const int quad = lane >> 4;
    const int l15  = lane & 15;
    const int wm   = (wave / WN) * (BM / WM);
    const int wn   = (wave % WN) * (BN / WN);
    const int m0   = blockIdx.y * BM;
    const int n0   = blockIdx.x * BN;
    const int xm   = l15 & (CH - 1);
    const bf16* __restrict__ W = p.W[blockIdx.z];

    f32x4 acc[TM][TN];
    #pragma unroll
    for (int i = 0; i < TM; ++i)
        #pragma unroll
        for (int j = 0; j < TN; ++j)
            acc[i][j] = f32x4{0.f, 0.f, 0.f, 0.f};

    auto stage = [&](int buf, int k0) {
        #pragma unroll
        for (int s = 0; s < BM * BK / 4096; ++s) {
            int base = s * 512 + wave * 64;
            int idx  = base + lane;
            int row  = idx / CH;
            int c    = idx % CH;
            gll16(A + (long)(m0 + row) * K + k0 + ((c ^ (row & (CH - 1))) * 8),
                  &As[buf][0][0] + (long)base * 8);
        }
        #pragma unroll
        for (int s = 0; s < BN * BK / 4096; ++s) {
            int base = s * 512 + wave * 64;
            int idx  = base + lane;
            int row  = idx / CH;
            int c    = idx % CH;
            gll16(W + (long)(n0 + row) * K + k0 + ((c ^ (row & (CH - 1))) * 8),
                  &Ws[buf][0][0] + (long)base * 8);
        }
    };

    stage(0, 0);
    int cur = 0;
    for (int k0 = 0; k0 < K; k0 += BK) {
        if (k0 + BK < K) {
            stage(cur ^ 1, k0 + BK);   // next tile's loads fly during MFMA
            asm volatile("s_waitcnt vmcnt(%0)" :: "i"(LPS) : "memory");
        } else {
            asm volatile("s_waitcnt vmcnt(0)" ::: "memory");
        }
        __builtin_amdgcn_s_barrier();
        __builtin_amdgcn_sched_barrier(0);

        bf16x8 a[TM][KK], b[TN][KK];
        #pragma unroll
        for (int i = 0; i < TM; ++i)
            #pragma unroll
            for (int kk = 0; kk < KK; ++kk)
                a[i][kk] = *(const bf16x8*)
                    &As[cur][wm + i * 16 + l15][((kk * 4 + quad) ^ xm) * 8];
        #pragma unroll
        for (int j = 0; j < TN; ++j)
            #pragma unroll
            for (int kk = 0; kk < KK; ++kk)
                b[j][kk] = *(const bf16x8*)
                    &Ws[cur][wn + j * 16 + l15][((kk * 4 + quad) ^ xm) * 8];
        __builtin_amdgcn_s_setprio(1);
        #pragma unroll
        for (int kk = 0; kk < KK; ++kk)
            #pragma unroll
            for (int i = 0; i < TM; ++i)
                #pragma unroll
                for (int j = 0; j < TN; ++j)
                    acc[i][j] = __builtin_amdgcn_mfma_f32_16x16x32_bf16(
                        a[i][kk], b[j][kk], acc[i][j], 0, 0, 0);
        __builtin_amdgcn_s_setprio(0);

        __builtin_amdgcn_sched_barrier(0);
        __builtin_amdgcn_s_barrier();
        cur ^= 1;
    }

    float* o32 = p.out32[blockIdx.z];
    bf16*  o16 = p.out16[blockIdx.z];
    const float* bias = p.bias[blockIdx.z];
    const float scl = p.scale[blockIdx.z];
    #pragma unroll
    for (int j = 0; j < TN; ++j) {
        int n = n0 + wn + j * 16 + l15;
        float bv = bias[n];
        #pragma unroll
        for (int i = 0; i < TM; ++i) {
            #pragma unroll
            for (int r = 0; r < 4; ++r) {
                int m = m0 + wm + i * 16 + quad * 4 + r;
                float v = (acc[i][j][r] + bv) * scl;
                if (relu) v = fmaxf(v, 0.f);
                if (o32) o32[(long)m * N + n] = v;
                if (o16) o16[(long)m * N + n] = f2bf(v);
            }
        }
    }
}

// ---------------------------------------------------------------------------
// Split-K GEMM, BK=64, same swizzle + dbuf + 512 threads. fp32 partials.
// ---------------------------------------------------------------------------
template<int BM, int BN, int BK, int KS, int WM>
__global__ __launch_bounds__(512) void gemm_splitk_k(
    const bf16* __restrict__ A, const bf16* __restrict__ W,
    float* __restrict__ part, int N, int K)
{
    constexpr int WN  = 8 / WM;
    constexpr int TM  = BM / WM / 16;
    constexpr int TN  = BN / WN / 16;
    constexpr int KK  = BK / 32;
    constexpr int CH  = BK / 8;
    constexpr int LPS = (BM + BN) * BK / 4096;
    __shared__ bf16 As[2][BM][BK];
    __shared__ bf16 Ws[2][BN][BK];

    const int t    = threadIdx.x;
    const int lane = t & 63;
    const int wave = t >> 6;
    const int quad = lane >> 4;
    const int l15  = lane & 15;
    const int wm   = (wave / WN) * (BM / WM);
    const int wn   = (wave % WN) * (BN / WN);
    const int m0   = blockIdx.y * BM;
    const int n0   = blockIdx.x * BN;
    const int xm   = l15 & (CH - 1);
    const int Kp   = K / KS;
    const int klo  = blockIdx.z * Kp;
    const long MN  = (long)gridDim.y * BM * N;

    f32x4 acc[TM][TN];
    #pragma unroll
    for (int i = 0; i < TM; ++i)
        #pragma unroll
        for (int j = 0; j < TN; ++j)
            acc[i][j] = f32x4{0.f, 0.f, 0.f, 0.f};

    auto stage = [&](int buf, int k0) {
        #pragma unroll
        for (int s = 0; s < BM * BK / 4096; ++s) {
            int base = s * 512 + wave * 64;
            int idx  = base + lane;
            int row  = idx / CH;
            int c    = idx % CH;
            gll16(A + (long)(m0 + row) * K + k0 + ((c ^ (row & (CH - 1))) * 8),
                  &As[buf][0][0] + (long)base * 8);
        }
        #pragma unroll
        for (int s = 0; s < BN * BK / 4096; ++s) {
            int base = s * 512 + wave * 64;
            int idx  = base + lane;
            int row  = idx / CH;
            int c    = idx % CH;
            gll16(W + (long)(n0 + row) * K + k0 + ((c ^ (row & (CH - 1))) * 8),
                  &Ws[buf][0][0] + (long)base * 8);
        }
    };

    stage(0, klo);
    int cur = 0;
    for (int k0 = klo; k0 < klo + Kp; k0 += BK) {
        if (k0 + BK < klo + Kp) {
            stage(cur ^ 1, k0 + BK);
            asm volatile("s_waitcnt vmcnt(%0)" :: "i"(LPS) : "memory");
        } else {
            asm volatile("s_waitcnt vmcnt(0)" ::: "memory");
        }
        __builtin_amdgcn_s_barrier();
        __builtin_amdgcn_sched_barrier(0);

        bf16x8 a[TM][KK], b[TN][KK];
        #pragma unroll
        for (int i = 0; i < TM; ++i)
            #pragma unroll
            for (int kk = 0; kk < KK; ++kk)
                a[i][kk] = *(const bf16x8*)
                    &As[cur][wm + i * 16 + l15][((kk * 4 + quad) ^ xm) * 8];
        #pragma unroll
        for (int j = 0; j < TN; ++j)
            #pragma unroll
            for (int kk = 0; kk < KK; ++kk)
                b[j][kk] = *(const bf16x8*)
                    &Ws[cur][wn + j * 16 + l15][((kk * 4 + quad) ^ xm) * 8];
        __builtin_amdgcn_s_setprio(1);
        #pragma unroll
        for (int kk = 0; kk < KK; ++kk)
            #pragma unroll
            for (int i = 0; i < TM; ++i)
                #pragma unroll
                for (int j = 0; j < TN; ++j)
                    acc[i][j] = __builtin_amdgcn_mfma_f32_16x16x32_bf16(
                        a[i][kk], b[j][kk], acc[i][j], 0, 0, 0);
        __builtin_amdgcn_s_setprio(0);

        __builtin_amdgcn_sched_barrier(0);
        __builtin_amdgcn_s_barrier();
        cur ^= 1;
    }

    float* o = part + (long)blockIdx.z * MN;
    #pragma unroll
    for (int j = 0; j < TN; ++j) {
        int n = n0 + wn + j * 16 + l15;
        #pragma unroll
        for (int i = 0; i < TM; ++i)
            #pragma unroll
            for (int r = 0; r < 4; ++r) {
                int m = m0 + wm + i * 16 + quad * 4 + r;
                o[(long)m * N + n] = acc[i][j][r];
            }
    }
}

// ---------------------------------------------------------------------------
// Flash attention, QBLK=128 x 8 waves (512 threads), KVSPLIT=2, XCD-swizzled.
// Swapped QK^T (P lane-local), pre-scaled Q, cvt_pk P-pack, gll16 K staging
// with pre-swizzled source cols (rule #21), pair-packed V transpose
// (v_perm_b32) into virtual-key order:
//   key i=[kt1 kt0 q1 q0 r1 r0] -> v(i)=[kt1 q1 q0 r1 r0 kt0].
// ---------------------------------------------------------------------------
__global__ __launch_bounds__(512) void attn_mfma_k(
    const bf16* __restrict__ Q, const bf16* __restrict__ Kg,
    const bf16* __restrict__ Vg, bf16* __restrict__ Opart,
    float* __restrict__ lpart)
{
    __shared__ bf16 Kb[64][64];   // linear, gll16-staged, col-XOR by row&7
    __shared__ bf16 Vt[64][72];   // transposed V, virtual-key order + XOR swz

    const int nwg = gridDim.x * gridDim.y * gridDim.z;
    const int wid = blockIdx.x + gridDim.x * (blockIdx.y + gridDim.y * blockIdx.z);
    const int sw  = xcd_swz(wid, nwg);
    const int bx  = sw % gridDim.x;
    const int rem = sw / gridDim.x;
    const int h   = rem % gridDim.y;
    const int spl = rem / gridDim.y;
    const int q0  = bx * 128;

    const int t    = threadIdx.x;
    const int lane = t & 63;
    const int wave = t >> 6;       // 0..7: 8 waves x 16 queries = 128
    const int quad = lane >> 4;
    const int l15  = lane & 15;
    const int cb   = h * DH;
    const long SD  = (long)SEQ * DM;

    const int qrow = q0 + wave * 16 + l15;
    bf16x8 bQ[2];
    #pragma unroll
    for (int kh = 0; kh < 2; ++kh)
        bQ[kh] = *(const bf16x8*)(Q + (long)qrow * DM + cb + kh * 32 + quad * 8);

    f32x4 o_acc[4];
    #pragma unroll
    for (int dt = 0; dt < 4; ++dt) o_acc[dt] = f32x4{0.f, 0.f, 0.f, 0.f};
    float lsum = 0.f;

    const int kv_lo = spl * (SEQ / KVSPLIT);
    const int kv_hi = kv_lo + SEQ / KVSPLIT;

    for (int kv0 = kv_lo; kv0 < kv_hi; kv0 += 64) {
        __syncthreads();
        // --- K: one gll16 round (512 lanes x 16B = 8KB tile) ---
        {
            int row = t >> 3;
            int dg  = t & 7;
            gll16(Kg + (long)(kv0 + row) * DM + cb + ((dg ^ (row & 7)) * 8),
                  &Kb[0][0] + (wave * 64) * 8);
        }
        // --- V: one round, 4 b32 pair-packed writes/thread ---
        {
            int i  = t;                    // 0..511
            int h4 = (i & 1) * 4;
            int dg = (i >> 1) & 7;
            int kp = i >> 4;               // 0..31 pair index
            int k0 = ((kp & 16) << 1) | (kp & 15);   // keys with bit4 == 0
            const bf16* vb = Vg + (long)(kv0 + k0) * DM + cb + dg * 8 + h4;
            uint2 a0 = *(const uint2*)vb;
            uint2 a1 = *(const uint2*)(vb + 16 * DM);
            int vk0 = (k0 & 32) | ((k0 & 15) << 1);
            int col = vk0 ^ (dg * 8);
            int d0  = dg * 8 + h4;
            *(unsigned*)&Vt[d0 + 0][col] = __builtin_amdgcn_perm(a1.x, a0.x, 0x05040100u);
            *(unsigned*)&Vt[d0 + 1][col] = __builtin_amdgcn_perm(a1.x, a0.x, 0x07060302u);
            *(unsigned*)&Vt[d0 + 2][col] = __builtin_amdgcn_perm(a1.y, a0.y, 0x05040100u);
            *(unsigned*)&Vt[d0 + 3][col] = __builtin_amdgcn_perm(a1.y, a0.y, 0x07060302u);
        }
        __syncthreads();

        // QK^T swapped: A = K rows (from LDS), B = Q.
        float p[16];
        #pragma unroll
        for (int kt = 0; kt < 4; ++kt) {
            int krow = kt * 16 + l15;
            bf16x8 a0 = *(const bf16x8*)&Kb[krow][(quad ^ (l15 & 7)) * 8];
            bf16x8 a1 = *(const bf16x8*)&Kb[krow][((4 + quad) ^ (l15 & 7)) * 8];
            f32x4 sv = f32x4{0.f, 0.f, 0.f, 0.f};
            sv = __builtin_amdgcn_mfma_f32_16x16x32_bf16(a0, bQ[0], sv, 0, 0, 0);
            sv = __builtin_amdgcn_mfma_f32_16x16x32_bf16(a1, bQ[1], sv, 0, 0, 0);
            #pragma unroll
            for (int r = 0; r < 4; ++r) p[kt * 4 + r] = exp2f(sv[r]);
        }

        #pragma unroll
        for (int i = 0; i < 16; ++i) lsum += p[i];

        // pack P into PV A-fragments: aP[c][j] = p[(2c+(j&1))*4 + (j>>1)]
        bf16x8 aP[2];
        #pragma unroll
        for (int c = 0; c < 2; ++c) {
            union { unsigned u[4]; bf16x8 v; } pk;
            #pragma unroll
            for (int w4 = 0; w4 < 4; ++w4)
                pk.u[w4] = cvt_pk_bf16(p[c * 8 + w4], p[c * 8 + 4 + w4]);
            aP[c] = pk.v;
        }

        #pragma unroll
        for (int dt = 0; dt < 4; ++dt) {
            int d   = dt * 16 + l15;
            int dgr = d >> 3;
            bf16x8 v0 = *(const bf16x8*)&Vt[d][(quad ^ dgr) * 8];
            bf16x8 v1 = *(const bf16x8*)&Vt[d][((4 + quad) ^ dgr) * 8];
            o_acc[dt] = __builtin_amdgcn_mfma_f32_16x16x32_bf16(aP[0], v0, o_acc[dt], 0, 0, 0);
            o_acc[dt] = __builtin_amdgcn_mfma_f32_16x16x32_bf16(aP[1], v1, o_acc[dt], 0, 0, 0);
        }
    }

    #pragma unroll
    for (int r = 0; r < 4; ++r) {
        int row = q0 + wave * 16 + quad * 4 + r;
        #pragma unroll
        for (int dt = 0; dt < 4; ++dt)
            Opart[(long)spl * SD + (long)row * DM + cb + dt * 16 + l15] =
                f2bf(o_acc[dt][r]);
    }
    lsum += __shfl_xor(lsum, 16);
    lsum += __shfl_xor(lsum, 32);
    if (quad == 0)
        lpart[((long)spl * NH + h) * SEQ + qrow] = lsum;
}

__global__ __launch_bounds__(256) void attn_reduce_k(
    const bf16* __restrict__ Opart, const float* __restrict__ lpart,
    bf16* __restrict__ O)
{
    const long SD = (long)SEQ * DM;
    long i = ((long)blockIdx.x * 256 + threadIdx.x) * 8;
    int row = (int)(i / DM);
    int h   = (int)((i % DM) / DH);

    float l = 0.f;
    #pragma unroll
    for (int k = 0; k < KVSPLIT; ++k)
        l += lpart[((long)k * NH + h) * SEQ + row];
    float inv = 1.f / l;

    float acc[8] = {};
    #pragma unroll
    for (int k = 0; k < KVSPLIT; ++k) {
        bf16x8 v = *(const bf16x8*)(Opart + (long)k * SD + i);
        #pragma unroll
        for (int j = 0; j < 8; ++j) acc[j] += (float)v[j];
    }
    bf16x8 o;
    #pragma unroll
    for (int j = 0; j < 8; ++j) o[j] = f2bf(acc[j] * inv);
    *(bf16x8*)(O + i) = o;
}

// ---------------------------------------------------------------------------
// Fused split-K reduce + bias + residual + LayerNorm. One block per row.
// ---------------------------------------------------------------------------
template<int NS>
__global__ __launch_bounds__(256) void ln_red_k(
    const float* __restrict__ part, const float* __restrict__ bias,
    const float* __restrict__ res, const float* __restrict__ g,
    const float* __restrict__ b, float* __restrict__ out32,
    bf16* __restrict__ out16)
{
    const long SD = (long)SEQ * DM;
    const int row = blockIdx.x;
    const int t   = threadIdx.x;
    const long off = (long)row * DM + (t << 2);

    float4 v = *(const float4*)(res + off);
    float4 bv0 = *(const float4*)(bias + (t << 2));
    v.x += bv0.x; v.y += bv0.y; v.z += bv0.z; v.w += bv0.w;
    #pragma unroll
    for (int z = 0; z < NS; ++z) {
        float4 pz = *(const float4*)(part + z * SD + off);
        v.x += pz.x; v.y += pz.y; v.z += pz.z; v.w += pz.w;
    }

    float s1 = v.x + v.y + v.z + v.w;
    float s2 = v.x * v.x + v.y * v.y + v.z * v.z + v.w * v.w;
    #pragma unroll
    for (int off2 = 32; off2 > 0; off2 >>= 1) {
        s1 += __shfl_xor(s1, off2);
        s2 += __shfl_xor(s2, off2);
    }
    __shared__ float red[8];
    int wid = t >> 6, lid = t & 63;
    if (lid == 0) { red[wid] = s1; red[4 + wid] = s2; }
    __syncthreads();
    s1 = red[0] + red[1] + red[2] + red[3];
    s2 = red[4] + red[5] + red[6] + red[7];

    float mu   = s1 * (1.f / DM);
    float var  = s2 * (1.f / DM) - mu * mu;
    float rstd = rsqrtf(var + 1e-5f);

    float4 gv = *(const float4*)(g + (t << 2));
    float4 bv = *(const float4*)(b + (t << 2));
    float4 ov;
    ov.x = (v.x - mu) * rstd * gv.x + bv.x;
    ov.y = (v.y - mu) * rstd * gv.y + bv.y;
    ov.z = (v.z - mu) * rstd * gv.z + bv.z;
    ov.w = (v.w - mu) * rstd * gv.w + bv.w;
    if (out32) *(float4*)(out32 + off) = ov;
    if (out16) {
        ushort4 o;
        o.x = f2bfu(ov.x); o.y = f2bfu(ov.y); o.z = f2bfu(ov.z); o.w = f2bfu(ov.w);
        *(ushort4*)((unsigned short*)out16 + off) = o;
    }
}

// ---------------------------------------------------------------------------
extern "C" void kernel_launch(void* const* d_in, const int* in_sizes, int n_in,
                              void* d_out, int out_size, void* d_ws, size_t ws_size,
                              hipStream_t stream)
{
    const float* x       = (const float*)d_in[0];
    const float* q_in_w  = (const float*)d_in[1];
    const float* q_in_b  = (const float*)d_in[2];
    const float* k_in_w  = (const float*)d_in[3];
    const float* k_in_b  = (const float*)d_in[4];
    const float* v_in_w  = (const float*)d_in[5];
    const float* v_in_b  = (const float*)d_in[6];
    const float* out_w   = (const float*)d_in[7];
    const float* out_b   = (const float*)d_in[8];
    const float* ffn1_w  = (const float*)d_in[9];
    const float* ffn1_b  = (const float*)d_in[10];
    const float* ffn2_w  = (const float*)d_in[11];
    const float* ffn2_b  = (const float*)d_in[12];
    const float* n1_g    = (const float*)d_in[13];
    const float* n1_b    = (const float*)d_in[14];
    const float* n2_g    = (const float*)d_in[15];
    const float* n2_b    = (const float*)d_in[16];
    const float* q_out_w = (const float*)d_in[17];
    const float* q_out_b = (const float*)d_in[18];
    const float* k_out_w = (const float*)d_in[19];
    const float* k_out_b = (const float*)d_in[20];
    const float* v_out_w = (const float*)d_in[21];
    const float* v_out_b = (const float*)d_in[22];

    float* out = (float*)d_out;
    const long SD = (long)SEQ * DM;
    const long MB = 1024 * 1024;

    // --- workspace layout, 48 MiB, lifetime-checked (Opart 8MB) ---
    char* w = (char*)d_ws;
    bf16*  xbf   = (bf16*)(w);
    float* lpart = (float*)(w);
    bf16*  qb    = (bf16*)(w + 4  * MB);
    bf16*  kb    = (bf16*)(w + 8  * MB);
    bf16*  vb    = (bf16*)(w + 12 * MB);
    bf16*  atnb  = (bf16*)(w + 16 * MB);
    float* h32   = (float*)(w);
    bf16*  h16   = (bf16*)(w + 8  * MB);
    float* P2    = (float*)(w + 8  * MB);
    bf16*  Opart = (bf16*)(w + 20 * MB);
    float* P1    = (float*)(w + 20 * MB);
    bf16*  f1    = (bf16*)(w + 24 * MB);
    bf16*  wqi   = (bf16*)(w + 32 * MB);
    bf16*  wki   = (bf16*)(w + 34 * MB);
    bf16*  wvi   = (bf16*)(w + 36 * MB);
    bf16*  wo    = (bf16*)(w + 38 * MB);
    bf16*  wf1   = (bf16*)(w + 40 * MB);
    bf16*  wf2   = (bf16*)(w + 40 * MB);
    bf16*  wqo   = (bf16*)(w + 24 * MB);
    bf16*  wko   = (bf16*)(w + 26 * MB);
    bf16*  wvo   = (bf16*)(w + 28 * MB);
    bf16*  ybf   = (bf16*)(w + 30 * MB);
    float* y32   = out + 3 * SD;

    dim3 blk(256);
    dim3 blk512(512);
    const int DD = DM * DM;
    const float SCL = 0.18033688f;   // 0.125 * log2(e), folded into Q

    // --- conv group 1: x + in/out-proj weights + ffn1 ---
    {
        ConvSegs cs;
        cs.s[0] = {x,      xbf, (int)SD};
        cs.s[1] = {q_in_w, wqi, DD};
        cs.s[2] = {k_in_w, wki, DD};
        cs.s[3] = {v_in_w, wvi, DD};
        cs.s[4] = {out_w,  wo,  DD};
        cs.s[5] = {ffn1_w, wf1, DM * DFF};
        conv_multi_k<<<dim3(DM * DFF / 1024, 6), blk, 0, stream>>>(cs);
    }

    // --- q/k/v in-projections (128x64 BK=64 dbuf, 768 blocks x 8 waves) ---
    {
        GemmPtrs p{};
        p.W[0] = wqi; p.W[1] = wki; p.W[2] = wvi;
        p.bias[0] = q_in_b; p.bias[1] = k_in_b; p.bias[2] = v_in_b;
        p.out16[0] = qb; p.out16[1] = kb; p.out16[2] = vb;
        p.scale[0] = SCL; p.scale[1] = 1.0f; p.scale[2] = 1.0f;
        gemm_bf16_k<128, 64, 64, 4><<<dim3(DM / 64, SEQ / 128, 3), blk512, 0, stream>>>(
            xbf, p, DM, DM, 0);
    }

    // --- attention: QBLK=128 x 8 waves, kv-split x2 (512 blocks) + reduce ---
    attn_mfma_k<<<dim3(SEQ / 128, NH, KVSPLIT), blk512, 0, stream>>>(
        qb, kb, vb, Opart, lpart);
    attn_reduce_k<<<dim3((int)(SD / 2048)), blk, 0, stream>>>(Opart, lpart, atnb);

    // --- out-projection, split-K=2 (64x128 BK=64 dbuf, 512 blocks x 8 waves) ---
    gemm_splitk_k<64, 128, 64, 2, 2><<<dim3(DM / 128, SEQ / 64, 2), blk512, 0, stream>>>(
        atnb, wo, P1, DM, DM);

    // --- LN1 fused reduce: h = LN(x + P1 + out_b) ---
    ln_red_k<2><<<SEQ, blk, 0, stream>>>(P1, out_b, x, n1_g, n1_b, h32, h16);

    // --- FFN1 (128x128 BK=64 dbuf, 512 blocks x 8 waves, relu) ---
    {
        GemmPtrs p{};
        p.W[0] = wf1; p.bias[0] = ffn1_b; p.out16[0] = f1;
        p.scale[0] = 1.0f; p.scale[1] = 1.0f; p.scale[2] = 1.0f;
        gemm_bf16_k<128, 128, 64, 2><<<dim3(DFF / 128, SEQ / 128, 1), blk512, 0, stream>>>(
            h16, p, DFF, DM, 1);
    }

    // --- conv wf2 (into dead wf1 region) ---
    conv_k<<<dim3(DM * DFF / 1024), blk, 0, stream>>>(ffn2_w, wf2, DM * DFF);

    // --- FFN2, split-K=2 (64x128 BK=64 dbuf, 512 blocks x 8 waves) -> P2 ---
    gemm_splitk_k<64, 128, 64, 2, 2><<<dim3(DM / 128, SEQ / 64, 2), blk512, 0, stream>>>(
        f1, wf2, P2, DM, DFF);

    // --- conv group 3 (into dead f1 region) ---
    {
        ConvSegs cs;
        cs.s[0] = {q_out_w, wqo, DD};
        cs.s[1] = {k_out_w, wko, DD};
        cs.s[2] = {v_out_w, wvo, DD};
        cs.s[3] = cs.s[0]; cs.s[4] = cs.s[0]; cs.s[5] = cs.s[0];
        conv_multi_k<<<dim3(DD / 1024, 3), blk, 0, stream>>>(cs);
    }

    // --- LN2 fused reduce: y = LN(h + P2 + ffn2_b) ---
    ln_red_k<2><<<SEQ, blk, 0, stream>>>(P2, ffn2_b, h32, n2_g, n2_b, y32, ybf);

    // --- next-layer projections (128x64 BK=64 dbuf, 768 blocks x 8 waves) ---
    {
        GemmPtrs p{};
        p.W[0] = wqo; p.W[1] = wko; p.W[2] = wvo;
        p.bias[0] = q_out_b; p.bias[1] = k_out_b; p.bias[2] = v_out_b;
        p.out32[0] = out; p.out32[1] = out + SD; p.out32[2] = out + 2 * SD;
        p.scale[0] = 1.0f; p.scale[1] = 1.0f; p.scale[2] = 1.0f;
        gemm_bf16_k<128, 64, 64, 4><<<dim3(DM / 64, SEQ / 128, 3), blk512, 0, stream>>>(
            ybf, p, DM, DM, 0);
    }
}